// Round 7
// baseline (447.625 us; speedup 1.0000x reference)
//
#include <hip/hip_runtime.h>

// NNMF fused: B=8192, NIN=3072, NOUT=512, 5 iterations.
// R13: W2 staged via global_load_lds DMA (zero-VGPR staging) + pre-swizzled
// W2 layout for bank-optimal LDS frag reads.
//  R11/R12 rocprof: slot time ~= SUM of pipe times (W L2 2340 + VALU 1230 +
//  LDS 1500 + MFMA 550 cy) -> no overlap. Cause: slot-persistent regs
//  w2v32+w1buf32+tacc32+h_reg32 = 128 exactly -> zero headroom, remat/spill
//  on every transient (R8-R10 falsified every occupancy-attribute fix).
//  Fix: w2v -> LDS via DMA (wave stages & reads its OWN 8KB slice; no
//  cross-wave hazard). Live set 96 + transients. DMA issued at region-1 top,
//  one vmcnt(0) before barrier A. W2 pre-swizzled in prep (b ^= ((b>>7)&7)<<4,
//  involution within each 1KB DMA window) so stride-32B frag reads hit all
//  8 bank windows (optimal for b128). Phase A acc chains split 2-way (R7).
//  Base structure = R11 (best measured, 255 us). Numerics identical.

#define NIN 3072
#define NOUT 512

using f32x4 = __attribute__((ext_vector_type(4))) float;
using i32x8 = __attribute__((ext_vector_type(8))) int;

union frag32 { i32x8 v; uint4 q[2]; };

#define MFMA128(A, B, C) \
    __builtin_amdgcn_mfma_scale_f32_16x16x128_f8f6f4( \
        (A), (B), (C), 0, 0, 0, (int)0x7f7f7f7f, 0, (int)0x7f7f7f7f)

__device__ __forceinline__ unsigned short f2bf(float f) {
    unsigned int u = __builtin_bit_cast(unsigned int, f);
    return (unsigned short)((u + 0x7fffu + ((u >> 16) & 1u)) >> 16);  // RNE
}
__device__ __forceinline__ float bf2f(unsigned short s) {
    unsigned int u = ((unsigned int)s) << 16;
    return __builtin_bit_cast(float, u);
}

// LDS-only barrier: cross-wave deps in the slot loop are LDS-only; global
// prefetches stay in flight (consumed by issuing wave, compiler inserts vmcnt).
#define LDS_BARRIER() do {                                   \
    asm volatile("s_waitcnt lgkmcnt(0)" ::: "memory");       \
    __builtin_amdgcn_s_barrier();                            \
    asm volatile("" ::: "memory");                           \
} while (0)

// ---------------------------------------------------------------------------
// prep_all: one launch, 8672 blocks x 256 threads.
//   blocks [0,8192)     : per-row x normalize (x16 pre-scale) -> bf16 X2
//   blocks [8192,8576)  : W -> W2 / W1 (fp8 e4m3, x4096, K=128 frag layout)
//   blocks [8576,8672)  : d0inv[k] = 1/(sum_n h0[n]*W[n][k] + 1e-20)
// K=128 fragment layouts (lane l holds 32 contiguous contraction elements,
// k = (l>>4)*32 + j):
//   W2 (Phase B B-op): linear byte b = ((s*32 + w*4 + nt)*64 + l)*32 + q*16 + j'
//     element: n = w*64 + nt*16 + (l&15), k = s*128 + (l>>4)*32 + (q*16+j')
//     STORED AT b ^ (((b>>7)&7)<<4)  [bank swizzle; involution in 1KB window]
//   W1 (Phase A B-op): addr = (((s*8 + w)*4 + c)*64 + l)*32 + j  (linear)
//     element: kout = s*128 + w*16 + (l&15), n = c*128 + (l>>4)*32 + j
// ---------------------------------------------------------------------------
__global__ void prep_all(const float* __restrict__ x,
                         const float* __restrict__ W,
                         const float* __restrict__ h_init,
                         unsigned short* __restrict__ X2,
                         unsigned char* __restrict__ W1,
                         unsigned char* __restrict__ W2,
                         float* __restrict__ d0inv) {
    __shared__ float wsum[4];
    __shared__ float dred[8][32];
    const int bb = blockIdx.x;
    const int t  = threadIdx.x;

    if (bb < 8192) {
        // ---- x row normalize -> bf16, pre-scaled x16 (exact: power of 2)
        const int b = bb;
        const float4* r4 = reinterpret_cast<const float4*>(x + (size_t)b * NIN);
        float s = 0.f;
        float4 v0 = r4[t], v1 = r4[t + 256], v2 = r4[t + 512];
        s = v0.x + v0.y + v0.z + v0.w + v1.x + v1.y + v1.z + v1.w + v2.x + v2.y + v2.z + v2.w;
        #pragma unroll
        for (int off = 32; off > 0; off >>= 1) s += __shfl_down(s, off, 64);
        int w = t >> 6, l = t & 63;
        if (l == 0) wsum[w] = s;
        __syncthreads();
        float inv = 16.0f / (wsum[0] + wsum[1] + wsum[2] + wsum[3] + 1e-20f);
        unsigned short* orow = X2 + (size_t)b * NIN;
        #pragma unroll
        for (int c = 0; c < 3; ++c) {
            float4 v = (c == 0) ? v0 : (c == 1) ? v1 : v2;
            ushort4 o;
            o.x = f2bf(v.x * inv); o.y = f2bf(v.y * inv);
            o.z = f2bf(v.z * inv); o.w = f2bf(v.w * inv);
            *reinterpret_cast<ushort4*>(orow + (t + c * 256) * 4) = o;
        }
    } else if (bb < 8192 + 384) {
        // ---- W quantization, K=128 frag layouts (32 B per thread)
        int tt = (bb - 8192) * 256 + t;       // 0 .. 98303
        unsigned int words[8];
        if (tt < 49152) {
            // W2: g = s*32 + w*4 + nt; swizzled store
            int l = tt & 63, g = tt >> 6;
            int s = g >> 5, rem = g & 31, w = rem >> 2, nt = rem & 3;
            int n = w * 64 + nt * 16 + (l & 15);
            int kbase = s * 128 + ((l >> 4) << 5);
            const float* src = W + (size_t)n * NIN + kbase;
            #pragma unroll
            for (int q = 0; q < 8; ++q) {
                float v0 = src[q * 4 + 0] * 4096.0f, v1 = src[q * 4 + 1] * 4096.0f;
                float v2 = src[q * 4 + 2] * 4096.0f, v3 = src[q * 4 + 3] * 4096.0f;
                int pk = __builtin_amdgcn_cvt_pk_fp8_f32(v0, v1, 0, false);
                pk     = __builtin_amdgcn_cvt_pk_fp8_f32(v2, v3, pk, true);
                words[q] = (unsigned int)pk;
            }
            unsigned int b0 = (unsigned int)tt * 32;
            unsigned int sw = ((b0 >> 7) & 7u) << 4;    // = ((l>>2)&7)<<4
            *reinterpret_cast<uint4*>(W2 + (b0 ^ sw)) =
                *reinterpret_cast<uint4*>(&words[0]);
            *reinterpret_cast<uint4*>(W2 + ((b0 | 16u) ^ sw)) =
                *reinterpret_cast<uint4*>(&words[4]);
        } else {
            // W1: g = (s*8 + w)*4 + c  (linear)
            int u = tt - 49152;
            int l = u & 63, g = u >> 6;
            int c = g & 3, sw = g >> 2;
            int w = sw & 7, s = sw >> 3;
            int kout = s * 128 + w * 16 + (l & 15);
            int nbase = c * 128 + ((l >> 4) << 5);
            #pragma unroll
            for (int q = 0; q < 8; ++q) {
                float v0 = W[(size_t)(nbase + q * 4 + 0) * NIN + kout] * 4096.0f;
                float v1 = W[(size_t)(nbase + q * 4 + 1) * NIN + kout] * 4096.0f;
                float v2 = W[(size_t)(nbase + q * 4 + 2) * NIN + kout] * 4096.0f;
                float v3 = W[(size_t)(nbase + q * 4 + 3) * NIN + kout] * 4096.0f;
                int pk = __builtin_amdgcn_cvt_pk_fp8_f32(v0, v1, 0, false);
                pk     = __builtin_amdgcn_cvt_pk_fp8_f32(v2, v3, pk, true);
                words[q] = (unsigned int)pk;
            }
            uint4* dst = reinterpret_cast<uint4*>(W1 + (size_t)u * 32);
            dst[0] = *reinterpret_cast<uint4*>(&words[0]);
            dst[1] = *reinterpret_cast<uint4*>(&words[4]);
        }
    } else {
        // ---- d0inv: block owns 32 k-cols; thread (kid = t&31, nsub = t>>5)
        int kb = bb - 8576;                   // 0..95
        int kid = t & 31, nsub = t >> 5;      // 8 n-chunks of 64
        int k = kb * 32 + kid;
        int n0 = nsub * 64;
        float s = 0.f;
        const float* p = W + (size_t)n0 * NIN + k;
        #pragma unroll 8
        for (int n = 0; n < 64; ++n) s += h_init[n0 + n] * p[(size_t)n * NIN];
        dred[nsub][kid] = s;
        __syncthreads();
        if (t < 32) {
            float sm = 1e-20f;
            #pragma unroll
            for (int j = 0; j < 8; ++j) sm += dred[j][t];
            d0inv[kb * 32 + t] = 1.0f / sm;
        }
    }
}

// ---------------------------------------------------------------------------
// Main kernel. 256 blocks x 512 threads (8 waves), 32 rows/block, 1 block/CU.
// R11 two-barrier slot structure; W2 via zero-VGPR LDS DMA; MX K=128 fp8.
// ---------------------------------------------------------------------------
__global__ __launch_bounds__(512, 1) void nnmf_main(
    const unsigned short* __restrict__ X2,
    const unsigned char* __restrict__ W1,
    const unsigned char* __restrict__ W2,
    const float* __restrict__ d0inv,
    const float* __restrict__ h_init,
    float* __restrict__ out)
{
    __shared__ unsigned char  w2stage[65536];    // 64 KB (W2[s], DMA-staged, swizzled)
    __shared__ unsigned char  h8_lds[32 * 528];  // 16.9 KB (fp8 h, x256)
    __shared__ unsigned short x_lds[32 * 136];   // 8.7 KB
    __shared__ unsigned char  r8_lds[32 * 144];  // 4.6 KB (fp8 r, stride 144B)
    __shared__ float red[8][32];
    // total 94.5 KB

    const int tid = threadIdx.x;
    const int w  = tid >> 6;        // wave 0..7
    const int l  = tid & 63;
    const int lo = l & 15;
    const int hi = l >> 4;          // 0..3
    const int b0 = blockIdx.x * 32;

    // fp32 h master in registers, C-layout: row=m*16+hi*4+i, col=w*64+nt*16+lo
    float h_reg[2][4][4];
    #pragma unroll
    for (int nt = 0; nt < 4; ++nt) {
        float hv = h_init[w * 64 + nt * 16 + lo];
        #pragma unroll
        for (int m = 0; m < 2; ++m)
            #pragma unroll
            for (int i = 0; i < 4; ++i)
                h_reg[m][nt][i] = hv;
    }

    // x staging: thread -> (row, 16B chunk)
    const int xrow = tid >> 4, xcc = tid & 15;
    const uint4* xg = reinterpret_cast<const uint4*>(X2 + (size_t)(b0 + xrow) * NIN + xcc * 8);
    unsigned short* xdst = &x_lds[xrow * 136 + xcc * 8];

    // W pointers
    const unsigned char* w1base = W1 + (size_t)w * 8192 + (size_t)l * 32;   // +s*65536 +c*2048
    const unsigned char* w2dma  = W2 + (size_t)w * 8192 + (size_t)l * 16;   // +s*65536 +j*1024
    // swizzled lane offset for w2stage frag reads (incl. bit-4 flip)
    const int slz = (l * 32) ^ (((l >> 2) & 7) << 4);
    const unsigned char* wsbase = w2stage + w * 8192;

    // prime pipeline: x[0] -> LDS, x[1] -> reg
    *reinterpret_cast<uint4*>(xdst) = xg[0];
    uint4 xnext = xg[16];
    frag32 w1buf[4];                // Phase A B-frags (valid from it0 s==23 on)
    __syncthreads();

    const float DSCL = 9.5367431640625e-07f;  // 2^-20: undo h x256 * W1 x4096
    const float TS   = 1.0f / 65536.0f;       // undo W2 x4096 and x-r x16 scales
    f32x4 tacc[2][4];

    for (int it = 0; it < 5; ++it) {
        #pragma unroll
        for (int m = 0; m < 2; ++m)
            #pragma unroll
            for (int nt = 0; nt < 4; ++nt)
                tacc[m][nt] = (f32x4){0.f, 0.f, 0.f, 0.f};

        for (int s = 0; s < 24; ++s) {
            const int sn  = (s + 1 == 24) ? 0 : s + 1;
            const int sn2 = (s + 2 >= 24) ? (s + 2 - 24) : s + 2;

            // ---- DMA W2[s] -> w2stage (zero VGPR; wave stages its own slice)
            {
                const unsigned char* gsrc = w2dma + (size_t)s * 65536;
                #pragma unroll
                for (int j = 0; j < 8; ++j) {
                    __builtin_amdgcn_global_load_lds(
                        (const __attribute__((address_space(1))) unsigned int*)(gsrc + j * 1024),
                        (__attribute__((address_space(3))) unsigned int*)(w2stage + w * 8192 + j * 1024),
                        16, 0, 0);
                }
            }

            // ---- issue x[s+2] prefetch
            uint4 xfut = xg[sn2 * 16];

            f32x4 d0, d1;
            float dv = 0.f;
            if (it == 0) {
                dv = d0inv[s * 128 + w * 16 + lo];   // exact it0 denom reciprocal
            } else {
                // ---- Phase A: h streamed from LDS, W1 register-resident,
                //      2-way split accumulator chains
                f32x4 a0a = {0,0,0,0}, a0b = {0,0,0,0}, a1a = {0,0,0,0}, a1b = {0,0,0,0};
                #pragma unroll
                for (int c = 0; c < 4; c += 2) {
                    frag32 h0a, h1a, h0b, h1b;
                    const uint4* p0a = reinterpret_cast<const uint4*>(
                        &h8_lds[lo * 528 + c * 128 + hi * 32]);
                    const uint4* p1a = reinterpret_cast<const uint4*>(
                        &h8_lds[(16 + lo) * 528 + c * 128 + hi * 32]);
                    const uint4* p0b = reinterpret_cast<const uint4*>(
                        &h8_lds[lo * 528 + (c + 1) * 128 + hi * 32]);
                    const uint4* p1b = reinterpret_cast<const uint4*>(
                        &h8_lds[(16 + lo) * 528 + (c + 1) * 128 + hi * 32]);
                    h0a.q[0] = p0a[0]; h0a.q[1] = p0a[1];
                    h1a.q[0] = p1a[0]; h1a.q[1] = p1a[1];
                    h0b.q[0] = p0b[0]; h0b.q[1] = p0b[1];
                    h1b.q[0] = p1b[0]; h1b.q[1] = p1b[1];
                    a0a = MFMA128(h0a.v, w1buf[c].v,     a0a);
                    a1a = MFMA128(h1a.v, w1buf[c].v,     a1a);
                    a0b = MFMA128(h0b.v, w1buf[c + 1].v, a0b);
                    a1b = MFMA128(h1b.v, w1buf[c + 1].v, a1b);
                }
                d0 = a0a + a0b;
                d1 = a1a + a1b;
            }

            // ---- r = x * rcp(denom + eps) -> fp8 in r8_lds  (x pre-scaled x16)
            #pragma unroll
            for (int i = 0; i < 4; ++i) {
                int row0 = hi * 4 + i;
                float x0 = bf2f(x_lds[row0 * 136 + w * 16 + lo]);
                float x1 = bf2f(x_lds[(16 + row0) * 136 + w * 16 + lo]);
                float r0, r1;
                if (it == 0) { r0 = x0 * dv; r1 = x1 * dv; }
                else {
                    r0 = x0 * __builtin_amdgcn_rcpf(fmaf(d0[i], DSCL, 1e-20f));
                    r1 = x1 * __builtin_amdgcn_rcpf(fmaf(d1[i], DSCL, 1e-20f));
                }
                int c0 = __builtin_amdgcn_cvt_pk_fp8_f32(r0, r0, 0, false);
                int c1 = __builtin_amdgcn_cvt_pk_fp8_f32(r1, r1, 0, false);
                r8_lds[row0 * 144 + w * 16 + lo] = (unsigned char)(c0 & 0xff);
                r8_lds[(16 + row0) * 144 + w * 16 + lo] = (unsigned char)(c1 & 0xff);
            }

            // ---- wait DMA complete (and drain stragglers), then barrier A
            asm volatile("s_waitcnt vmcnt(0)" ::: "memory");
            __builtin_amdgcn_sched_barrier(0);
            LDS_BARRIER();   // barrier A

            // ---- Phase B: r8 frags x staged W2 frags (swizzled reads)
            frag32 ra0, ra1;
            {
                const uint4* p0 = reinterpret_cast<const uint4*>(&r8_lds[lo * 144 + hi * 32]);
                const uint4* p1 = reinterpret_cast<const uint4*>(&r8_lds[(16 + lo) * 144 + hi * 32]);
                ra0.q[0] = p0[0]; ra0.q[1] = p0[1];
                ra1.q[0] = p1[0]; ra1.q[1] = p1[1];
            }
            #pragma unroll
            for (int nt = 0; nt < 2; ++nt) {
                frag32 wf;
                wf.q[0] = *reinterpret_cast<const uint4*>(wsbase + nt * 2048 + slz);
                wf.q[1] = *reinterpret_cast<const uint4*>(wsbase + nt * 2048 + (slz ^ 16));
                tacc[0][nt] = MFMA128(ra0.v, wf.v, tacc[0][nt]);
                tacc[1][nt] = MFMA128(ra1.v, wf.v, tacc[1][nt]);
            }

            // ---- reload w1buf = W1[sn] (skip during it0 except last slot)
            if (it > 0 || s == 23) {
                const unsigned char* w1p = w1base + (size_t)sn * 65536;
                #pragma unroll
                for (int c = 0; c < 4; ++c) {
                    const uint4* p = reinterpret_cast<const uint4*>(w1p + c * 2048);
                    w1buf[c].q[0] = p[0];
                    w1buf[c].q[1] = p[1];
                }
            }

            #pragma unroll
            for (int nt = 2; nt < 4; ++nt) {
                frag32 wf;
                wf.q[0] = *reinterpret_cast<const uint4*>(wsbase + nt * 2048 + slz);
                wf.q[1] = *reinterpret_cast<const uint4*>(wsbase + nt * 2048 + (slz ^ 16));
                tacc[0][nt] = MFMA128(ra0.v, wf.v, tacc[0][nt]);
                tacc[1][nt] = MFMA128(ra1.v, wf.v, tacc[1][nt]);
            }

            // ---- stage x[s+1] (loaded a slot+ ago), rotate prefetch regs
            *reinterpret_cast<uint4*>(xdst) = xnext;
            xnext = xfut;
            LDS_BARRIER();   // barrier B
        }

        // ---- boundary: h_new = normalize(h * (1 + t*2^-16)), fp32 in regs
        float p[2][4];
        #pragma unroll
        for (int m = 0; m < 2; ++m)
            #pragma unroll
            for (int i = 0; i < 4; ++i) p[m][i] = 0.f;

        #pragma unroll
        for (int m = 0; m < 2; ++m)
            #pragma unroll
            for (int nt = 0; nt < 4; ++nt)
                #pragma unroll
                for (int i = 0; i < 4; ++i) {
                    float v = h_reg[m][nt][i] * (1.f + tacc[m][nt][i] * TS);  // EPSILON_0 = 1
                    h_reg[m][nt][i] = v;
                    p[m][i] += v;
                }
        #pragma unroll
        for (int mask = 1; mask < 16; mask <<= 1)
            #pragma unroll
            for (int m = 0; m < 2; ++m)
                #pragma unroll
                for (int i = 0; i < 4; ++i)
                    p[m][i] += __shfl_xor(p[m][i], mask, 64);
        if (lo == 0) {
            #pragma unroll
            for (int m = 0; m < 2; ++m)
                #pragma unroll
                for (int i = 0; i < 4; ++i)
                    red[w][m * 16 + hi * 4 + i] = p[m][i];
        }
        __syncthreads();
        float inv[2][4];
        #pragma unroll
        for (int m = 0; m < 2; ++m)
            #pragma unroll
            for (int i = 0; i < 4; ++i) {
                int row = m * 16 + hi * 4 + i;
                float S = 0.f;
                #pragma unroll
                for (int ww = 0; ww < 8; ++ww) S += red[ww][row];
                inv[m][i] = 1.f / (S + 1e-20f);
            }

        if (it < 4) {
            #pragma unroll
            for (int m = 0; m < 2; ++m)
                #pragma unroll
                for (int nt = 0; nt < 4; ++nt)
                    #pragma unroll
                    for (int i = 0; i < 4; ++i) {
                        int row = m * 16 + hi * 4 + i;
                        int col = w * 64 + nt * 16 + lo;
                        float hv = h_reg[m][nt][i] * inv[m][i];
                        h_reg[m][nt][i] = hv;
                        int c = __builtin_amdgcn_cvt_pk_fp8_f32(hv * 256.0f, hv * 256.0f, 0, false);
                        h8_lds[row * 528 + col] = (unsigned char)(c & 0xff);
                    }
            __syncthreads();
        } else {
            #pragma unroll
            for (int m = 0; m < 2; ++m)
                #pragma unroll
                for (int nt = 0; nt < 4; ++nt)
                    #pragma unroll
                    for (int i = 0; i < 4; ++i) {
                        int row = m * 16 + hi * 4 + i;
                        int col = w * 64 + nt * 16 + lo;
                        out[(size_t)(b0 + row) * 512 + col] = h_reg[m][nt][i] * inv[m][i];
                    }
        }
    }
}

extern "C" void kernel_launch(void* const* d_in, const int* in_sizes, int n_in,
                              void* d_out, int out_size, void* d_ws, size_t ws_size,
                              hipStream_t stream) {
    const float* x   = (const float*)d_in[0];   // [8192][3072]
    const float* wgt = (const float*)d_in[1];   // [512][3072]
    const float* h0  = (const float*)d_in[2];   // [512]
    float* out = (float*)d_out;

    // ws: X2 bf16 50,331,648 | W1 fp8 1,572,864 | W2 fp8 1,572,864 | d0inv 12,288
    unsigned short* X2 = (unsigned short*)d_ws;
    unsigned char*  W1 = (unsigned char*)((char*)d_ws + 50331648);
    unsigned char*  W2 = (unsigned char*)((char*)d_ws + 51904512);
    float* d0inv       = (float*)((char*)d_ws + 53477376);

    prep_all<<<8672, 256, 0, stream>>>(x, wgt, h0, X2, W1, W2, d0inv);
    nnmf_main<<<256, 512, 0, stream>>>(X2, W1, W2, d0inv, h0, out);
}

// Round 8
// 391.236 us; speedup vs baseline: 1.1441x; 1.1441x over previous
//
#include <hip/hip_runtime.h>

// NNMF fused: B=8192, NIN=3072, NOUT=512, 5 iterations.
// R14: R11 base + fp32-h-master -> LDS to free 32 registers.
//  R11 (best, 255 us): slot ~= SUM of pipes (W-L2 2340 + LDS 1700 + VALU
//  1230 + MFMA 1100 cy) -> no overlap. Cause: slot-persistent regs
//  w2v32+w1buf32+tacc32+h_reg32 = 128 exactly -> allocator sinks the w2v
//  loads to their use site after barrier A (no spare dest regs in Phase A),
//  so every load stalls serially at L2 latency.
//  R13 (DMA+swizzle, 314 us) falsified the LDS-staging route: swizzle added
//  conflicts (1.0e7->2.4e7), vmcnt(0) drained all prefetch, +64KB/slot LDS.
//  R14 change: h master in h32_lds (boundary-only access, R12-proven safe,
//  identical numerics) -> persistent set 96. Phase A rewritten with minimal
//  transients (single-c loop: 2 ha frags + d0/d1 = 24 regs). In-flight peak
//  ~124 <= 128 -> w2v/W1/x loads ride across Phase A + r-conv (~2500 cy
//  cover vs ~300 cy L2 latency). No swizzle, no DMA, no vmcnt(0).

#define NIN 3072
#define NOUT 512

using f32x4 = __attribute__((ext_vector_type(4))) float;
using i32x8 = __attribute__((ext_vector_type(8))) int;

union frag32 { i32x8 v; uint4 q[2]; };

#define MFMA128(A, B, C) \
    __builtin_amdgcn_mfma_scale_f32_16x16x128_f8f6f4( \
        (A), (B), (C), 0, 0, 0, (int)0x7f7f7f7f, 0, (int)0x7f7f7f7f)

__device__ __forceinline__ unsigned short f2bf(float f) {
    unsigned int u = __builtin_bit_cast(unsigned int, f);
    return (unsigned short)((u + 0x7fffu + ((u >> 16) & 1u)) >> 16);  // RNE
}
__device__ __forceinline__ float bf2f(unsigned short s) {
    unsigned int u = ((unsigned int)s) << 16;
    return __builtin_bit_cast(float, u);
}

// LDS-only barrier: cross-wave deps in the slot loop are LDS-only; global
// prefetches stay in flight (consumed by issuing wave, compiler inserts vmcnt).
#define LDS_BARRIER() do {                                   \
    asm volatile("s_waitcnt lgkmcnt(0)" ::: "memory");       \
    __builtin_amdgcn_s_barrier();                            \
    asm volatile("" ::: "memory");                           \
} while (0)

// ---------------------------------------------------------------------------
// prep_all: one launch, 8672 blocks x 256 threads.
//   blocks [0,8192)     : per-row x normalize (x16 pre-scale) -> bf16 X2
//   blocks [8192,8576)  : W -> W2 / W1 (fp8 e4m3, x4096, K=128 frag layout)
//   blocks [8576,8672)  : d0inv[k] = 1/(sum_n h0[n]*W[n][k] + 1e-20)
// K=128 fragment layouts (lane l holds 32 contiguous contraction elements,
// k = (l>>4)*32 + j):
//   W2 (Phase B B-op): addr = ((s*32 + w*4 + nt)*64 + l)*32 + j   (LINEAR)
//     element: n = w*64 + nt*16 + (l&15), k = s*128 + (l>>4)*32 + j
//   W1 (Phase A B-op): addr = (((s*8 + w)*4 + c)*64 + l)*32 + j   (LINEAR)
//     element: kout = s*128 + w*16 + (l&15), n = c*128 + (l>>4)*32 + j
// ---------------------------------------------------------------------------
__global__ void prep_all(const float* __restrict__ x,
                         const float* __restrict__ W,
                         const float* __restrict__ h_init,
                         unsigned short* __restrict__ X2,
                         unsigned char* __restrict__ W1,
                         unsigned char* __restrict__ W2,
                         float* __restrict__ d0inv) {
    __shared__ float wsum[4];
    __shared__ float dred[8][32];
    const int bb = blockIdx.x;
    const int t  = threadIdx.x;

    if (bb < 8192) {
        // ---- x row normalize -> bf16, pre-scaled x16 (exact: power of 2)
        const int b = bb;
        const float4* r4 = reinterpret_cast<const float4*>(x + (size_t)b * NIN);
        float s = 0.f;
        float4 v0 = r4[t], v1 = r4[t + 256], v2 = r4[t + 512];
        s = v0.x + v0.y + v0.z + v0.w + v1.x + v1.y + v1.z + v1.w + v2.x + v2.y + v2.z + v2.w;
        #pragma unroll
        for (int off = 32; off > 0; off >>= 1) s += __shfl_down(s, off, 64);
        int w = t >> 6, l = t & 63;
        if (l == 0) wsum[w] = s;
        __syncthreads();
        float inv = 16.0f / (wsum[0] + wsum[1] + wsum[2] + wsum[3] + 1e-20f);
        unsigned short* orow = X2 + (size_t)b * NIN;
        #pragma unroll
        for (int c = 0; c < 3; ++c) {
            float4 v = (c == 0) ? v0 : (c == 1) ? v1 : v2;
            ushort4 o;
            o.x = f2bf(v.x * inv); o.y = f2bf(v.y * inv);
            o.z = f2bf(v.z * inv); o.w = f2bf(v.w * inv);
            *reinterpret_cast<ushort4*>(orow + (t + c * 256) * 4) = o;
        }
    } else if (bb < 8192 + 384) {
        // ---- W quantization, K=128 frag layouts (32 B per thread)
        int tt = (bb - 8192) * 256 + t;       // 0 .. 98303
        unsigned int words[8];
        if (tt < 49152) {
            // W2: g = s*32 + w*4 + nt  (linear store)
            int l = tt & 63, g = tt >> 6;
            int s = g >> 5, rem = g & 31, w = rem >> 2, nt = rem & 3;
            int n = w * 64 + nt * 16 + (l & 15);
            int kbase = s * 128 + ((l >> 4) << 5);
            const float* src = W + (size_t)n * NIN + kbase;
            #pragma unroll
            for (int q = 0; q < 8; ++q) {
                float v0 = src[q * 4 + 0] * 4096.0f, v1 = src[q * 4 + 1] * 4096.0f;
                float v2 = src[q * 4 + 2] * 4096.0f, v3 = src[q * 4 + 3] * 4096.0f;
                int pk = __builtin_amdgcn_cvt_pk_fp8_f32(v0, v1, 0, false);
                pk     = __builtin_amdgcn_cvt_pk_fp8_f32(v2, v3, pk, true);
                words[q] = (unsigned int)pk;
            }
            uint4* dst = reinterpret_cast<uint4*>(W2 + (size_t)tt * 32);
            dst[0] = *reinterpret_cast<uint4*>(&words[0]);
            dst[1] = *reinterpret_cast<uint4*>(&words[4]);
        } else {
            // W1: g = (s*8 + w)*4 + c  (linear store)
            int u = tt - 49152;
            int l = u & 63, g = u >> 6;
            int c = g & 3, sw = g >> 2;
            int w = sw & 7, s = sw >> 3;
            int kout = s * 128 + w * 16 + (l & 15);
            int nbase = c * 128 + ((l >> 4) << 5);
            #pragma unroll
            for (int q = 0; q < 8; ++q) {
                float v0 = W[(size_t)(nbase + q * 4 + 0) * NIN + kout] * 4096.0f;
                float v1 = W[(size_t)(nbase + q * 4 + 1) * NIN + kout] * 4096.0f;
                float v2 = W[(size_t)(nbase + q * 4 + 2) * NIN + kout] * 4096.0f;
                float v3 = W[(size_t)(nbase + q * 4 + 3) * NIN + kout] * 4096.0f;
                int pk = __builtin_amdgcn_cvt_pk_fp8_f32(v0, v1, 0, false);
                pk     = __builtin_amdgcn_cvt_pk_fp8_f32(v2, v3, pk, true);
                words[q] = (unsigned int)pk;
            }
            uint4* dst = reinterpret_cast<uint4*>(W1 + (size_t)u * 32);
            dst[0] = *reinterpret_cast<uint4*>(&words[0]);
            dst[1] = *reinterpret_cast<uint4*>(&words[4]);
        }
    } else {
        // ---- d0inv: block owns 32 k-cols; thread (kid = t&31, nsub = t>>5)
        int kb = bb - 8576;                   // 0..95
        int kid = t & 31, nsub = t >> 5;      // 8 n-chunks of 64
        int k = kb * 32 + kid;
        int n0 = nsub * 64;
        float s = 0.f;
        const float* p = W + (size_t)n0 * NIN + k;
        #pragma unroll 8
        for (int n = 0; n < 64; ++n) s += h_init[n0 + n] * p[(size_t)n * NIN];
        dred[nsub][kid] = s;
        __syncthreads();
        if (t < 32) {
            float sm = 1e-20f;
            #pragma unroll
            for (int j = 0; j < 8; ++j) sm += dred[j][t];
            d0inv[kb * 32 + t] = 1.0f / sm;
        }
    }
}

// ---------------------------------------------------------------------------
// Main kernel. 256 blocks x 512 threads (8 waves), 32 rows/block, 1 block/CU.
// R11 two-barrier slot structure; h master in LDS; MX K=128 fp8 MFMA.
// ---------------------------------------------------------------------------
__global__ __launch_bounds__(512, 1) void nnmf_main(
    const unsigned short* __restrict__ X2,
    const unsigned char* __restrict__ W1,
    const unsigned char* __restrict__ W2,
    const float* __restrict__ d0inv,
    const float* __restrict__ h_init,
    float* __restrict__ out)
{
    __shared__ unsigned char  h8_lds[32 * 528];   // 16.9 KB (fp8 h, x256)
    __shared__ float          h32_lds[32 * 516];  // 66.0 KB (fp32 h master)
    __shared__ unsigned short x_lds[32 * 136];    //  8.7 KB
    __shared__ unsigned char  r8_lds[32 * 144];   //  4.6 KB (fp8 r, stride 144B)
    __shared__ float red[8][32];
    // total ~97.3 KB

    const int tid = threadIdx.x;
    const int w  = tid >> 6;        // wave 0..7
    const int l  = tid & 63;
    const int lo = l & 15;
    const int hi = l >> 4;          // 0..3
    const int b0 = blockIdx.x * 32;

    // fp32 h master init (LDS; each (row,col) owned by one thread at boundary)
    for (int idx = tid; idx < 32 * 512; idx += 512) {
        int r = idx >> 9, c = idx & 511;
        h32_lds[r * 516 + c] = h_init[c];
    }

    // x staging: thread -> (row, 16B chunk)
    const int xrow = tid >> 4, xcc = tid & 15;
    const uint4* xg = reinterpret_cast<const uint4*>(X2 + (size_t)(b0 + xrow) * NIN + xcc * 8);
    unsigned short* xdst = &x_lds[xrow * 136 + xcc * 8];

    // W pointers (fp8, K=128 frag layouts; 32-B aligned per lane)
    const unsigned char* w1base = W1 + (size_t)w * 8192 + (size_t)l * 32;   // +s*65536 +c*2048
    const unsigned char* w2base = W2 + (size_t)w * 8192 + (size_t)l * 32;   // +s*65536 +nt*2048

    // prime pipeline: x[0] -> LDS, x[1] -> reg
    *reinterpret_cast<uint4*>(xdst) = xg[0];
    uint4 xnext = xg[16];
    frag32 w1buf[4];                // Phase A B-frags (valid from it0 s==23 on)
    __syncthreads();

    const float DSCL = 9.5367431640625e-07f;  // 2^-20: undo h x256 * W1 x4096
    const float TS   = 1.0f / 65536.0f;       // undo W2 x4096 and x-r x16 scales
    f32x4 tacc[2][4];

    for (int it = 0; it < 5; ++it) {
        #pragma unroll
        for (int m = 0; m < 2; ++m)
            #pragma unroll
            for (int nt = 0; nt < 4; ++nt)
                tacc[m][nt] = (f32x4){0.f, 0.f, 0.f, 0.f};

        for (int s = 0; s < 24; ++s) {
            const int sn  = (s + 1 == 24) ? 0 : s + 1;
            const int sn2 = (s + 2 >= 24) ? (s + 2 - 24) : s + 2;

            // ---- issue W2[s] loads (4 x 32B frags; consumed after barrier A;
            //      with 96-reg persistent set these stay in flight over Phase A)
            frag32 w2v[4];
            {
                const unsigned char* w2p = w2base + (size_t)s * 65536;
                #pragma unroll
                for (int nt = 0; nt < 4; ++nt) {
                    const uint4* p = reinterpret_cast<const uint4*>(w2p + nt * 2048);
                    w2v[nt].q[0] = p[0];
                    w2v[nt].q[1] = p[1];
                }
            }

            f32x4 d0 = {0,0,0,0}, d1 = {0,0,0,0};
            float dv = 0.f;
            if (it == 0) {
                dv = d0inv[s * 128 + w * 16 + lo];   // exact it0 denom reciprocal
            } else {
                // ---- Phase A: minimal transients (2 ha frags + d0/d1 live)
                #pragma unroll
                for (int c = 0; c < 4; ++c) {
                    frag32 ha0, ha1;
                    const uint4* p0 = reinterpret_cast<const uint4*>(
                        &h8_lds[lo * 528 + c * 128 + hi * 32]);
                    const uint4* p1 = reinterpret_cast<const uint4*>(
                        &h8_lds[(16 + lo) * 528 + c * 128 + hi * 32]);
                    ha0.q[0] = p0[0]; ha0.q[1] = p0[1];
                    ha1.q[0] = p1[0]; ha1.q[1] = p1[1];
                    d0 = MFMA128(ha0.v, w1buf[c].v, d0);
                    d1 = MFMA128(ha1.v, w1buf[c].v, d1);
                }
            }

            // ---- r = x * rcp(denom + eps) -> fp8 in r8_lds  (x pre-scaled x16)
            #pragma unroll
            for (int i = 0; i < 4; ++i) {
                int row0 = hi * 4 + i;
                float x0 = bf2f(x_lds[row0 * 136 + w * 16 + lo]);
                float x1 = bf2f(x_lds[(16 + row0) * 136 + w * 16 + lo]);
                float r0, r1;
                if (it == 0) { r0 = x0 * dv; r1 = x1 * dv; }
                else {
                    r0 = x0 * __builtin_amdgcn_rcpf(fmaf(d0[i], DSCL, 1e-20f));
                    r1 = x1 * __builtin_amdgcn_rcpf(fmaf(d1[i], DSCL, 1e-20f));
                }
                int c0 = __builtin_amdgcn_cvt_pk_fp8_f32(r0, r0, 0, false);
                int c1 = __builtin_amdgcn_cvt_pk_fp8_f32(r1, r1, 0, false);
                r8_lds[row0 * 144 + w * 16 + lo] = (unsigned char)(c0 & 0xff);
                r8_lds[(16 + row0) * 144 + w * 16 + lo] = (unsigned char)(c1 & 0xff);
            }
            LDS_BARRIER();   // barrier A (LDS-only: global prefetches stay in flight)

            // ---- Phase B: r8 frags x w2v (registers)
            frag32 ra0, ra1;
            {
                const uint4* p0 = reinterpret_cast<const uint4*>(&r8_lds[lo * 144 + hi * 32]);
                const uint4* p1 = reinterpret_cast<const uint4*>(&r8_lds[(16 + lo) * 144 + hi * 32]);
                ra0.q[0] = p0[0]; ra0.q[1] = p0[1];
                ra1.q[0] = p1[0]; ra1.q[1] = p1[1];
            }
            #pragma unroll
            for (int nt = 0; nt < 2; ++nt) {
                tacc[0][nt] = MFMA128(ra0.v, w2v[nt].v, tacc[0][nt]);
                tacc[1][nt] = MFMA128(ra1.v, w2v[nt].v, tacc[1][nt]);
            }

            // ---- reload w1buf = W1[sn] (skip during it0 except last slot)
            if (it > 0 || s == 23) {
                const unsigned char* w1p = w1base + (size_t)sn * 65536;
                #pragma unroll
                for (int c = 0; c < 4; ++c) {
                    const uint4* p = reinterpret_cast<const uint4*>(w1p + c * 2048);
                    w1buf[c].q[0] = p[0];
                    w1buf[c].q[1] = p[1];
                }
            }

            #pragma unroll
            for (int nt = 2; nt < 4; ++nt) {
                tacc[0][nt] = MFMA128(ra0.v, w2v[nt].v, tacc[0][nt]);
                tacc[1][nt] = MFMA128(ra1.v, w2v[nt].v, tacc[1][nt]);
            }

            // ---- stage x[s+1] (loaded last slot), issue x[s+2]
            *reinterpret_cast<uint4*>(xdst) = xnext;
            xnext = xg[(size_t)sn2 * 16];
            LDS_BARRIER();   // barrier B
        }

        // ---- boundary: h_new = normalize(h * (1 + t*2^-16)), fp32 master in LDS
        float hv_[2][4][4];
        float p[2][4];
        #pragma unroll
        for (int m = 0; m < 2; ++m)
            #pragma unroll
            for (int i = 0; i < 4; ++i) p[m][i] = 0.f;

        #pragma unroll
        for (int m = 0; m < 2; ++m)
            #pragma unroll
            for (int nt = 0; nt < 4; ++nt)
                #pragma unroll
                for (int i = 0; i < 4; ++i) {
                    int row = m * 16 + hi * 4 + i;
                    int col = w * 64 + nt * 16 + lo;
                    float hv = h32_lds[row * 516 + col];
                    float v = hv * (1.f + tacc[m][nt][i] * TS);  // EPSILON_0 = 1
                    hv_[m][nt][i] = v;
                    p[m][i] += v;
                }
        #pragma unroll
        for (int mask = 1; mask < 16; mask <<= 1)
            #pragma unroll
            for (int m = 0; m < 2; ++m)
                #pragma unroll
                for (int i = 0; i < 4; ++i)
                    p[m][i] += __shfl_xor(p[m][i], mask, 64);
        if (lo == 0) {
            #pragma unroll
            for (int m = 0; m < 2; ++m)
                #pragma unroll
                for (int i = 0; i < 4; ++i)
                    red[w][m * 16 + hi * 4 + i] = p[m][i];
        }
        __syncthreads();
        float inv[2][4];
        #pragma unroll
        for (int m = 0; m < 2; ++m)
            #pragma unroll
            for (int i = 0; i < 4; ++i) {
                int row = m * 16 + hi * 4 + i;
                float S = 0.f;
                #pragma unroll
                for (int ww = 0; ww < 8; ++ww) S += red[ww][row];
                inv[m][i] = 1.f / (S + 1e-20f);
            }

        if (it < 4) {
            #pragma unroll
            for (int m = 0; m < 2; ++m)
                #pragma unroll
                for (int nt = 0; nt < 4; ++nt)
                    #pragma unroll
                    for (int i = 0; i < 4; ++i) {
                        int row = m * 16 + hi * 4 + i;
                        int col = w * 64 + nt * 16 + lo;
                        float hv = hv_[m][nt][i] * inv[m][i];
                        h32_lds[row * 516 + col] = hv;
                        int c = __builtin_amdgcn_cvt_pk_fp8_f32(hv * 256.0f, hv * 256.0f, 0, false);
                        h8_lds[row * 528 + col] = (unsigned char)(c & 0xff);
                    }
            __syncthreads();
        } else {
            #pragma unroll
            for (int m = 0; m < 2; ++m)
                #pragma unroll
                for (int nt = 0; nt < 4; ++nt)
                    #pragma unroll
                    for (int i = 0; i < 4; ++i) {
                        int row = m * 16 + hi * 4 + i;
                        int col = w * 64 + nt * 16 + lo;
                        out[(size_t)(b0 + row) * 512 + col] = hv_[m][nt][i] * inv[m][i];
                    }
        }
    }
}

extern "C" void kernel_launch(void* const* d_in, const int* in_sizes, int n_in,
                              void* d_out, int out_size, void* d_ws, size_t ws_size,
                              hipStream_t stream) {
    const float* x   = (const float*)d_in[0];   // [8192][3072]
    const float* wgt = (const float*)d_in[1];   // [512][3072]
    const float* h0  = (const float*)d_in[2];   // [512]
    float* out = (float*)d_out;

    // ws: X2 bf16 50,331,648 | W1 fp8 1,572,864 | W2 fp8 1,572,864 | d0inv 12,288
    unsigned short* X2 = (unsigned short*)d_ws;
    unsigned char*  W1 = (unsigned char*)((char*)d_ws + 50331648);
    unsigned char*  W2 = (unsigned char*)((char*)d_ws + 51904512);
    float* d0inv       = (float*)((char*)d_ws + 53477376);

    prep_all<<<8672, 256, 0, stream>>>(x, wgt, h0, X2, W1, W2, d0inv);
    nnmf_main<<<256, 512, 0, stream>>>(X2, W1, W2, d0inv, h0, out);
}